// Round 7
// baseline (67.307 us; speedup 1.0000x reference)
//
#include <hip/hip_runtime.h>
#include <hip/hip_bf16.h>

#define BC 4
#define NQ 1200
#define DIM 256
#define NH 8
#define HD 32
#define E3 768
#define MROWS (BC*NQ)
#define SCALE 0.17677669529663687f
#define L2E 1.4426950408889634f
#define SL2E (SCALE * L2E)

// VT2 global layout: [b][h][hh(2)][chunk(160)][d16(16)][8 keys]
#define VT2_PER_BH 40960
#define VT2_PER_HH 20480

typedef __attribute__((ext_vector_type(8))) short bf16x8;
typedef __attribute__((ext_vector_type(4))) float f32x4;

__device__ inline short f2bf(float f) {
    __hip_bfloat16 h = __float2bfloat16(f);
    return *reinterpret_cast<short*>(&h);
}
__device__ inline unsigned pack2bf(float a, float b) {
    unsigned ua = (unsigned short)f2bf(a);
    unsigned ub = (unsigned short)f2bf(b);
    return ua | (ub << 16);
}

// ---------------- beta (f32 exact) + center packing ----------------
__global__ void beta_ctr_kernel(const float* __restrict__ feat, const float* __restrict__ bw,
                                const float* __restrict__ bb, const float* __restrict__ bbox,
                                float* __restrict__ beta, float* __restrict__ ctr) {
    int gw = (blockIdx.x * 256 + threadIdx.x) >> 6;   // one wave per (b,n)
    int lane = threadIdx.x & 63;
    if (gw >= MROWS) return;
    const float* frow = feat + (size_t)gw * DIM;
    float acc[NH];
#pragma unroll
    for (int h = 0; h < NH; ++h) acc[h] = 0.f;
#pragma unroll
    for (int it = 0; it < DIM / 64; ++it) {
        int d = it * 64 + lane;
        float f = frow[d];
#pragma unroll
        for (int h = 0; h < NH; ++h) acc[h] += f * bw[h * DIM + d];
    }
#pragma unroll
    for (int h = 0; h < NH; ++h) {
#pragma unroll
        for (int off = 32; off; off >>= 1) acc[h] += __shfl_xor(acc[h], off);
    }
    int b = gw / NQ, n = gw % NQ;
#pragma unroll
    for (int h = 0; h < NH; ++h) {
        float v = acc[h] + bb[h];
        if (lane == h) beta[(b * NH + h) * NQ + n] = v;
    }
    if (lane == 0) {
        ctr[gw * 2]     = bbox[(size_t)gw * 10];
        ctr[gw * 2 + 1] = bbox[(size_t)gw * 10 + 1];
    }
}

// ---------------- GEMM: C[M,E] = A[M,256] * W[E,256]^T + bias ----------------
// QSCALE: scale W rows e<256 (the Q projection) by SCALE*log2e in f32 before bf16.
// VTOUT: rows e in [512,768) (V projection) go to VT2 chunked-transposed layout.
template<bool AF32, bool BF32, bool OUTF32, bool VTOUT, bool QSCALE>
__global__ __launch_bounds__(256) void gemm_k256(const void* __restrict__ Av,
                                                 const void* __restrict__ Bv,
                                                 const float* __restrict__ bias,
                                                 void* __restrict__ Cout, int Edim,
                                                 short* __restrict__ vtout) {
    __shared__ short as[64][40];
    __shared__ short bs[64][40];
    int m0 = blockIdx.y * 64, e0 = blockIdx.x * 64;
    int t = threadIdx.x, lane = t & 63, wid = t >> 6;
    int wr = (wid >> 1) * 32, wc = (wid & 1) * 32;
    f32x4 acc[2][2] = {};
    int lrow = t >> 2, lch = t & 3;
    const float qs = (QSCALE && e0 < DIM) ? SL2E : 1.f;

    for (int ks = 0; ks < DIM / 32; ++ks) {
        bf16x8 av, wv;
        if (AF32) {
            const float* A = (const float*)Av;
            float4 f0 = *(const float4*)(A + (size_t)(m0 + lrow) * DIM + ks * 32 + lch * 8);
            float4 f1 = *(const float4*)(A + (size_t)(m0 + lrow) * DIM + ks * 32 + lch * 8 + 4);
            av[0]=f2bf(f0.x); av[1]=f2bf(f0.y); av[2]=f2bf(f0.z); av[3]=f2bf(f0.w);
            av[4]=f2bf(f1.x); av[5]=f2bf(f1.y); av[6]=f2bf(f1.z); av[7]=f2bf(f1.w);
        } else {
            av = *(const bf16x8*)((const short*)Av + (size_t)(m0 + lrow) * DIM + ks * 32 + lch * 8);
        }
        if (BF32) {
            const float* B = (const float*)Bv;
            float4 f0 = *(const float4*)(B + (size_t)(e0 + lrow) * DIM + ks * 32 + lch * 8);
            float4 f1 = *(const float4*)(B + (size_t)(e0 + lrow) * DIM + ks * 32 + lch * 8 + 4);
            wv[0]=f2bf(f0.x*qs); wv[1]=f2bf(f0.y*qs); wv[2]=f2bf(f0.z*qs); wv[3]=f2bf(f0.w*qs);
            wv[4]=f2bf(f1.x*qs); wv[5]=f2bf(f1.y*qs); wv[6]=f2bf(f1.z*qs); wv[7]=f2bf(f1.w*qs);
        } else {
            wv = *(const bf16x8*)((const short*)Bv + (size_t)(e0 + lrow) * DIM + ks * 32 + lch * 8);
        }
        __syncthreads();
        *(bf16x8*)&as[lrow][lch * 8] = av;
        *(bf16x8*)&bs[lrow][lch * 8] = wv;
        __syncthreads();
#pragma unroll
        for (int sm = 0; sm < 2; ++sm) {
            bf16x8 af = *(const bf16x8*)&as[wr + sm * 16 + (lane & 15)][(lane >> 4) * 8];
#pragma unroll
            for (int sn = 0; sn < 2; ++sn) {
                bf16x8 bfv = *(const bf16x8*)&bs[wc + sn * 16 + (lane & 15)][(lane >> 4) * 8];
                acc[sm][sn] = __builtin_amdgcn_mfma_f32_16x16x32_bf16(af, bfv, acc[sm][sn], 0, 0, 0);
            }
        }
    }
#pragma unroll
    for (int sm = 0; sm < 2; ++sm)
#pragma unroll
        for (int sn = 0; sn < 2; ++sn) {
            int e = e0 + wc + sn * 16 + (lane & 15);
            float bv = bias[e];
            if (QSCALE && e < DIM) bv *= SL2E;
            float vals[4];
            int mbase = m0 + wr + sm * 16 + (lane >> 4) * 4;
#pragma unroll
            for (int r = 0; r < 4; ++r) vals[r] = acc[sm][sn][r] + bv;
            if (VTOUT && e >= 2 * DIM) {
                int dv = e - 2 * DIM;
                int hv = dv >> 5, dd = dv & 31;
                int hh = dd >> 4, di = dd & 15;
                int bb = mbase / NQ, nn = mbase - bb * NQ;   // 4-key group never crosses b
                short4 o;
                o.x = f2bf(vals[0]); o.y = f2bf(vals[1]);
                o.z = f2bf(vals[2]); o.w = f2bf(vals[3]);
                size_t off = (size_t)(bb * NH + hv) * VT2_PER_BH + hh * VT2_PER_HH
                           + (nn >> 3) * 128 + di * 8 + (nn & 7);
                *(short4*)&vtout[off] = o;
            } else {
#pragma unroll
                for (int r = 0; r < 4; ++r) {
                    int m = mbase + r;
                    if (OUTF32) ((float*)Cout)[(size_t)m * Edim + e] = vals[r];
                    else        ((short*)Cout)[(size_t)m * Edim + e] = f2bf(vals[r]);
                }
            }
        }
}

// ---------------- fused flash attention ----------------
// grid: (75, B*H); block 256 = 4 waves, ALL on the same 16 q-rows, 4-way key
// split (32 keys/wave per 128-key tile). Cooperative LDS staging (conflict-free
// 16B-block layouts), T14 reg-staged prefetch, T13 defer-max, Q pre-scaled.
#define KT_OFF 0
#define VT_OFF 8192
#define CK_OFF 16384
#define PL_OFF 17408
__global__ __launch_bounds__(256, 6) void attn_kernel(const short* __restrict__ qkv,
                                                      const short* __restrict__ vt2,
                                                      const float* __restrict__ beta,
                                                      const float* __restrict__ ctr,
                                                      short* __restrict__ attnb) {
    __shared__ __align__(16) char smem[21504];

    const int t = threadIdx.x, lane = t & 63, w = t >> 6;
    const int g = lane >> 4, i = lane & 15;
    const int ksp = w;                       // 4-way key split
    const int bh = blockIdx.y, b = bh >> 3, h = bh & 7;
    const int q = blockIdx.x * 16 + i;       // always < NQ (75*16 = 1200)
    const int kwb = ksp * 32;
    const int bq = b * NQ;

    bf16x8 qf = *(const bf16x8*)(qkv + (size_t)(bq + q) * E3 + h * HD + g * 8);  // pre-scaled
    const float cqx = ctr[(bq + q) * 2];
    const float cqy = ctr[(bq + q) * 2 + 1];
    const float nbql = -beta[(b * NH + h) * NQ + q] * L2E;

    float mcur = -1e30f, lsum = 0.f;
    f32x4 o0 = {}, o1 = {};

    const short* kgb = qkv + (size_t)bq * E3 + DIM + h * HD;
    const short* vgb = vt2 + (size_t)bh * VT2_PER_BH;
    const float* cgb = ctr + (size_t)bq * 2;

    bf16x8 sk0, sk1, sv0, sv1;
    float2 sc2;

    auto stage_load = [&](int kb) {
        int i0 = t, i1 = t + 256;
        int r0 = min(kb + ((i0 >> 6) << 4) + (i0 & 15), NQ - 1);
        int r1 = min(kb + ((i1 >> 6) << 4) + (i1 & 15), NQ - 1);
        sk0 = *(const bf16x8*)(kgb + (size_t)r0 * E3 + ((i0 >> 4) & 3) * 8);
        sk1 = *(const bf16x8*)(kgb + (size_t)r1 * E3 + ((i1 >> 4) & 3) * 8);
        sv0 = *(const bf16x8*)(vgb + (i0 >> 8) * VT2_PER_HH + ((kb >> 3) + ((i0 >> 4) & 15)) * 128 + (i0 & 15) * 8);
        sv1 = *(const bf16x8*)(vgb + (i1 >> 8) * VT2_PER_HH + ((kb >> 3) + ((i1 >> 4) & 15)) * 128 + (i1 & 15) * 8);
        if (t < 128) {
            int ky = min(kb + t, NQ - 1);
            sc2 = *(const float2*)(cgb + ky * 2);
        }
    };
    auto stage_write = [&]() {
        *(bf16x8*)&smem[KT_OFF + t * 16]         = sk0;
        *(bf16x8*)&smem[KT_OFF + (t + 256) * 16] = sk1;
        *(bf16x8*)&smem[VT_OFF + t * 16]         = sv0;
        *(bf16x8*)&smem[VT_OFF + (t + 256) * 16] = sv1;
        if (t < 128) *(float2*)&smem[CK_OFF + t * 8] = sc2;
    };

    stage_load(0);
    stage_write();
    __syncthreads();

    for (int kb = 0; kb < NQ; kb += 128) {
        const bool haveNext = (kb + 128 < NQ);
        const bool tail = (kb + 128 > NQ);
        if (haveNext) stage_load(kb + 128);   // issue early; latency hides under compute

        // ---- QK^T + distance mask (conflict-free K frags), 32 keys/wave ----
        float st[8];
#pragma unroll
        for (int kcl = 0; kcl < 2; ++kcl) {
            bf16x8 af = *(const bf16x8*)&smem[KT_OFF + ((((ksp * 2 + kcl) << 6) + lane) << 4)];
            f32x4 zero = {};
            f32x4 s = __builtin_amdgcn_mfma_f32_16x16x32_bf16(af, qf, zero, 0, 0, 0);
            int lk = kwb + kcl * 16 + 4 * g;
            float4 cA = *(const float4*)&smem[CK_OFF + lk * 8];
            float4 cB = *(const float4*)&smem[CK_OFF + lk * 8 + 16];
            float cxv[4] = {cA.x, cA.z, cB.x, cB.z};
            float cyv[4] = {cA.y, cA.w, cB.y, cB.w};
#pragma unroll
            for (int r = 0; r < 4; ++r) {
                float dx = cqx - cxv[r], dy = cqy - cyv[r];
                float d2 = __builtin_fmaf(dx, dx, dy * dy);
                float dist = __builtin_amdgcn_sqrtf(d2);
                st[kcl * 4 + r] = __builtin_fmaf(dist, nbql, s[r]);
            }
            if (tail) {
#pragma unroll
                for (int r = 0; r < 4; ++r)
                    if (kb + lk + r >= NQ) st[kcl * 4 + r] = -1e30f;
            }
        }

        // ---- online softmax: tree max (7 ops) + 2 shfl, T13 defer-max ----
        float m01 = fmaxf(st[0], st[1]), m23 = fmaxf(st[2], st[3]);
        float m45 = fmaxf(st[4], st[5]), m67 = fmaxf(st[6], st[7]);
        float vm = fmaxf(fmaxf(m01, m23), fmaxf(m45, m67));
        vm = fmaxf(vm, __shfl_xor(vm, 16));
        vm = fmaxf(vm, __shfl_xor(vm, 32));
        if (!__all(vm <= mcur + 8.0f)) {
            float mnew = fmaxf(mcur, vm);
            float al = __builtin_amdgcn_exp2f(mcur - mnew);
            mcur = mnew;
            lsum *= al;
#pragma unroll
            for (int r = 0; r < 4; ++r) { o0[r] *= al; o1[r] *= al; }
        }
#pragma unroll
        for (int x = 0; x < 8; ++x) st[x] = __builtin_amdgcn_exp2f(st[x] - mcur);
        float rs = ((st[0] + st[1]) + (st[2] + st[3])) + ((st[4] + st[5]) + (st[6] + st[7]));
        rs += __shfl_xor(rs, 16);
        rs += __shfl_xor(rs, 32);
        lsum += rs;

        // ---- P -> wave-private LDS, chunked layout [c(4)][q(16)][8 keys] ----
#pragma unroll
        for (int kcl = 0; kcl < 2; ++kcl) {
            int offb = PL_OFF + (w << 10) + ((2 * kcl + (g >> 1)) << 8) + (i << 4) + ((g & 1) << 3);
            *(unsigned*)&smem[offb]     = pack2bf(st[kcl * 4 + 0], st[kcl * 4 + 1]);
            *(unsigned*)&smem[offb + 4] = pack2bf(st[kcl * 4 + 2], st[kcl * 4 + 3]);
        }

        // ---- PV: one 16x16x32 MFMA per d-half (32 keys = full K) ----
        {
            bf16x8 pbf = *(const bf16x8*)&smem[PL_OFF + (w << 10) + (g << 8) + (i << 4)];
            int vidx = (((ksp << 2) + g) << 4) + i;
            bf16x8 vf0 = *(const bf16x8*)&smem[VT_OFF + (vidx << 4)];
            bf16x8 vf1 = *(const bf16x8*)&smem[VT_OFF + 4096 + (vidx << 4)];
            o0 = __builtin_amdgcn_mfma_f32_16x16x32_bf16(vf0, pbf, o0, 0, 0, 0);
            o1 = __builtin_amdgcn_mfma_f32_16x16x32_bf16(vf1, pbf, o1, 0, 0, 0);
        }

        if (haveNext) {
            __syncthreads();     // all waves done reading current tile
            stage_write();
            __syncthreads();     // next tile visible
        }
    }

    // ---- merge the four key-splits (overlays smem -> barrier) ----
    __syncthreads();
    float* mrg = (float*)smem;                 // [4][64][10]
    float* my = mrg + (w * 64 + lane) * 10;
    my[0] = mcur; my[1] = lsum;
#pragma unroll
    for (int r = 0; r < 4; ++r) { my[2 + r] = o0[r]; my[6 + r] = o1[r]; }
    __syncthreads();
    if (w < 2) {
        const float* p0 = mrg + lane * 10;
        const float* p1 = mrg + (64 + lane) * 10;
        const float* p2 = mrg + (128 + lane) * 10;
        const float* p3 = mrg + (192 + lane) * 10;
        float mN = fmaxf(fmaxf(p0[0], p1[0]), fmaxf(p2[0], p3[0]));
        float a0 = __builtin_amdgcn_exp2f(p0[0] - mN);
        float a1 = __builtin_amdgcn_exp2f(p1[0] - mN);
        float a2 = __builtin_amdgcn_exp2f(p2[0] - mN);
        float a3 = __builtin_amdgcn_exp2f(p3[0] - mN);
        float inv = 1.f / (p0[1] * a0 + p1[1] * a1 + p2[1] * a2 + p3[1] * a3);
        int hh = w;                            // wave 0 -> d 0-15, wave 1 -> d 16-31
        short4 outv;
        float vals[4];
#pragma unroll
        for (int r = 0; r < 4; ++r) {
            int o = 2 + hh * 4 + r;
            vals[r] = (p0[o] * a0 + p1[o] * a1 + p2[o] * a2 + p3[o] * a3) * inv;
        }
        outv.x = f2bf(vals[0]); outv.y = f2bf(vals[1]);
        outv.z = f2bf(vals[2]); outv.w = f2bf(vals[3]);
        *(short4*)&attnb[(size_t)(bq + q) * DIM + h * HD + hh * 16 + 4 * g] = outv;
    }
}

extern "C" void kernel_launch(void* const* d_in, const int* in_sizes, int n_in,
                              void* d_out, int out_size, void* d_ws, size_t ws_size,
                              hipStream_t stream) {
    const float* bbox  = (const float*)d_in[0];
    const float* feat  = (const float*)d_in[1];
    const float* bw    = (const float*)d_in[2];
    const float* bb    = (const float*)d_in[3];
    const float* in_w  = (const float*)d_in[4];
    const float* in_b  = (const float*)d_in[5];
    const float* out_w = (const float*)d_in[6];
    const float* out_b = (const float*)d_in[7];
    float* out = (float*)d_out;

    char* ws = (char*)d_ws;
    size_t off = 0;
    auto alloc = [&](size_t bytes) { void* p = ws + off; off += (bytes + 255) & ~255ull; return p; };
    short* qkvb  = (short*)alloc((size_t)MROWS * E3 * 2);
    short* vtb   = (short*)alloc((size_t)BC * NH * VT2_PER_BH * 2);
    short* attnb = (short*)alloc((size_t)MROWS * DIM * 2);
    float* betab = (float*)alloc((size_t)BC * NH * NQ * 4);
    float* ctr   = (float*)alloc((size_t)BC * NQ * 2 * 4 + 1024);
    (void)ws_size; (void)in_sizes; (void)n_in; (void)out_size;

    beta_ctr_kernel<<<MROWS / 4, 256, 0, stream>>>(feat, bw, bb, bbox, betab, ctr);
    gemm_k256<true, true, false, true, true><<<dim3(E3 / 64, MROWS / 64), 256, 0, stream>>>(feat, in_w, in_b, qkvb, E3, vtb);
    attn_kernel<<<dim3(75, BC * NH), 256, 0, stream>>>(qkvb, vtb, betab, ctr, attnb);
    gemm_k256<false, true, true, false, false><<<dim3(DIM / 64, MROWS / 64), 256, 0, stream>>>(attnb, out_w, out_b, out, DIM, nullptr);
}

// Round 8
// 60.733 us; speedup vs baseline: 1.1082x; 1.1082x over previous
//
#include <hip/hip_runtime.h>
#include <hip/hip_bf16.h>

#define BC 4
#define NQ 1200
#define DIM 256
#define NH 8
#define HD 32
#define E3 768
#define MROWS (BC*NQ)
#define SCALE 0.17677669529663687f
#define L2E 1.4426950408889634f
#define SL2E (SCALE * L2E)

// VT2 global layout: [b][h][hh(2)][chunk(160)][d16(16)][8 keys]
#define VT2_PER_BH 40960
#define VT2_PER_HH 20480

typedef __attribute__((ext_vector_type(8))) short bf16x8;
typedef __attribute__((ext_vector_type(4))) float f32x4;
typedef __attribute__((ext_vector_type(2))) unsigned u32x2;

__device__ inline short f2bf(float f) {
    __hip_bfloat16 h = __float2bfloat16(f);
    return *reinterpret_cast<short*>(&h);
}
__device__ inline unsigned pack2bf(float a, float b) {
    unsigned ua = (unsigned short)f2bf(a);
    unsigned ub = (unsigned short)f2bf(b);
    return ua | (ub << 16);
}

// ---------------- beta (f32 exact) + center packing ----------------
__global__ void beta_ctr_kernel(const float* __restrict__ feat, const float* __restrict__ bw,
                                const float* __restrict__ bb, const float* __restrict__ bbox,
                                float* __restrict__ beta, float* __restrict__ ctr) {
    int gw = (blockIdx.x * 256 + threadIdx.x) >> 6;   // one wave per (b,n)
    int lane = threadIdx.x & 63;
    if (gw >= MROWS) return;
    const float* frow = feat + (size_t)gw * DIM;
    float acc[NH];
#pragma unroll
    for (int h = 0; h < NH; ++h) acc[h] = 0.f;
#pragma unroll
    for (int it = 0; it < DIM / 64; ++it) {
        int d = it * 64 + lane;
        float f = frow[d];
#pragma unroll
        for (int h = 0; h < NH; ++h) acc[h] += f * bw[h * DIM + d];
    }
#pragma unroll
    for (int h = 0; h < NH; ++h) {
#pragma unroll
        for (int off = 32; off; off >>= 1) acc[h] += __shfl_xor(acc[h], off);
    }
    int b = gw / NQ, n = gw % NQ;
#pragma unroll
    for (int h = 0; h < NH; ++h) {
        float v = acc[h] + bb[h];
        if (lane == h) beta[(b * NH + h) * NQ + n] = v;
    }
    if (lane == 0) {
        ctr[gw * 2]     = bbox[(size_t)gw * 10];
        ctr[gw * 2 + 1] = bbox[(size_t)gw * 10 + 1];
    }
}

// ---------------- GEMM: C[M,E] = A[M,256] * W[E,256]^T + bias ----------------
template<bool AF32, bool BF32, bool OUTF32, bool VTOUT, bool QSCALE>
__global__ __launch_bounds__(256) void gemm_k256(const void* __restrict__ Av,
                                                 const void* __restrict__ Bv,
                                                 const float* __restrict__ bias,
                                                 void* __restrict__ Cout, int Edim,
                                                 short* __restrict__ vtout) {
    __shared__ short as[64][40];
    __shared__ short bs[64][40];
    int m0 = blockIdx.y * 64, e0 = blockIdx.x * 64;
    int t = threadIdx.x, lane = t & 63, wid = t >> 6;
    int wr = (wid >> 1) * 32, wc = (wid & 1) * 32;
    f32x4 acc[2][2] = {};
    int lrow = t >> 2, lch = t & 3;
    const float qs = (QSCALE && e0 < DIM) ? SL2E : 1.f;

    for (int ks = 0; ks < DIM / 32; ++ks) {
        bf16x8 av, wv;
        if (AF32) {
            const float* A = (const float*)Av;
            float4 f0 = *(const float4*)(A + (size_t)(m0 + lrow) * DIM + ks * 32 + lch * 8);
            float4 f1 = *(const float4*)(A + (size_t)(m0 + lrow) * DIM + ks * 32 + lch * 8 + 4);
            av[0]=f2bf(f0.x); av[1]=f2bf(f0.y); av[2]=f2bf(f0.z); av[3]=f2bf(f0.w);
            av[4]=f2bf(f1.x); av[5]=f2bf(f1.y); av[6]=f2bf(f1.z); av[7]=f2bf(f1.w);
        } else {
            av = *(const bf16x8*)((const short*)Av + (size_t)(m0 + lrow) * DIM + ks * 32 + lch * 8);
        }
        if (BF32) {
            const float* B = (const float*)Bv;
            float4 f0 = *(const float4*)(B + (size_t)(e0 + lrow) * DIM + ks * 32 + lch * 8);
            float4 f1 = *(const float4*)(B + (size_t)(e0 + lrow) * DIM + ks * 32 + lch * 8 + 4);
            wv[0]=f2bf(f0.x*qs); wv[1]=f2bf(f0.y*qs); wv[2]=f2bf(f0.z*qs); wv[3]=f2bf(f0.w*qs);
            wv[4]=f2bf(f1.x*qs); wv[5]=f2bf(f1.y*qs); wv[6]=f2bf(f1.z*qs); wv[7]=f2bf(f1.w*qs);
        } else {
            wv = *(const bf16x8*)((const short*)Bv + (size_t)(e0 + lrow) * DIM + ks * 32 + lch * 8);
        }
        __syncthreads();
        *(bf16x8*)&as[lrow][lch * 8] = av;
        *(bf16x8*)&bs[lrow][lch * 8] = wv;
        __syncthreads();
#pragma unroll
        for (int sm = 0; sm < 2; ++sm) {
            bf16x8 af = *(const bf16x8*)&as[wr + sm * 16 + (lane & 15)][(lane >> 4) * 8];
#pragma unroll
            for (int sn = 0; sn < 2; ++sn) {
                bf16x8 bfv = *(const bf16x8*)&bs[wc + sn * 16 + (lane & 15)][(lane >> 4) * 8];
                acc[sm][sn] = __builtin_amdgcn_mfma_f32_16x16x32_bf16(af, bfv, acc[sm][sn], 0, 0, 0);
            }
        }
    }
#pragma unroll
    for (int sm = 0; sm < 2; ++sm)
#pragma unroll
        for (int sn = 0; sn < 2; ++sn) {
            int e = e0 + wc + sn * 16 + (lane & 15);
            float bv = bias[e];
            if (QSCALE && e < DIM) bv *= SL2E;
            float vals[4];
            int mbase = m0 + wr + sm * 16 + (lane >> 4) * 4;
#pragma unroll
            for (int r = 0; r < 4; ++r) vals[r] = acc[sm][sn][r] + bv;
            if (VTOUT && e >= 2 * DIM) {
                int dv = e - 2 * DIM;
                int hv = dv >> 5, dd = dv & 31;
                int hh = dd >> 4, di = dd & 15;
                int bb = mbase / NQ, nn = mbase - bb * NQ;   // 4-key group never crosses b
                short4 o;
                o.x = f2bf(vals[0]); o.y = f2bf(vals[1]);
                o.z = f2bf(vals[2]); o.w = f2bf(vals[3]);
                size_t off = (size_t)(bb * NH + hv) * VT2_PER_BH + hh * VT2_PER_HH
                           + (nn >> 3) * 128 + di * 8 + (nn & 7);
                *(short4*)&vtout[off] = o;
            } else {
#pragma unroll
                for (int r = 0; r < 4; ++r) {
                    int m = mbase + r;
                    if (OUTF32) ((float*)Cout)[(size_t)m * Edim + e] = vals[r];
                    else        ((short*)Cout)[(size_t)m * Edim + e] = f2bf(vals[r]);
                }
            }
        }
}

// ---------------- fused flash attention ----------------
// grid: (38, B*H); block 256 = 4 waves = 2 qgroup x 2 ksplit; wave-tile 16q x 64k.
// Double-buffered K/V/CK staging (ONE barrier per tile), T14 reg-staged prefetch,
// T13 defer-max with MFMA C-init = -mcur, Q pre-scaled in GEMM.
#define BUFSZ 17408
#define KT_OFF 0
#define VT_OFF 8192
#define CK_OFF 16384
#define PL_OFF (2*BUFSZ)
__global__ __launch_bounds__(256, 4) void attn_kernel(const short* __restrict__ qkv,
                                                      const short* __restrict__ vt2,
                                                      const float* __restrict__ beta,
                                                      const float* __restrict__ ctr,
                                                      short* __restrict__ attnb) {
    __shared__ __align__(16) char smem[2 * BUFSZ + 4096];   // 38912 B

    const int t = threadIdx.x, lane = t & 63, w = t >> 6;
    const int g = lane >> 4, i = lane & 15;
    const int qg = w >> 1, ksp = w & 1;
    const int bh = blockIdx.y, b = bh >> 3, h = bh & 7;
    const int q0 = blockIdx.x * 32 + qg * 16;
    const int q = q0 + i, qc = min(q, NQ - 1);
    const int kwb = ksp * 64;
    const int bq = b * NQ;

    bf16x8 qf = *(const bf16x8*)(qkv + (size_t)(bq + qc) * E3 + h * HD + g * 8);  // pre-scaled
    const float cqx = ctr[(bq + qc) * 2];
    const float cqy = ctr[(bq + qc) * 2 + 1];
    const float nbql = -beta[(b * NH + h) * NQ + qc] * L2E;

    float mcur = 0.f, lsum = 0.f;                  // mcur=0 safe: self-key keeps max >= ~0
    f32x4 o0 = {}, o1 = {};

    // staging source pointers (advance per tile; no clamps — OOB lands in owned ws, masked)
    const int koff = ((t >> 6) << 4) + (t & 15);
    const short* kld0 = qkv + (size_t)bq * E3 + DIM + h * HD + (size_t)koff * E3 + ((t >> 4) & 3) * 8;
    const short* kld1 = kld0 + (size_t)64 * E3;
    const short* vld0 = vt2 + (size_t)bh * VT2_PER_BH + (((t >> 4) & 15)) * 128 + (t & 15) * 8;
    const short* vld1 = vld0 + VT2_PER_HH;
    const float* cld = ctr + (size_t)bq * 2 + t * 2;

    bf16x8 sk0, sk1, sv0, sv1;
    float2 sc2;
    auto stage_load = [&]() {
        sk0 = *(const bf16x8*)kld0;
        sk1 = *(const bf16x8*)kld1;
        sv0 = *(const bf16x8*)vld0;
        sv1 = *(const bf16x8*)vld1;
        if (t < 128) sc2 = *(const float2*)cld;
        kld0 += (size_t)128 * E3; kld1 += (size_t)128 * E3;
        vld0 += 2048; vld1 += 2048; cld += 256;
    };
    auto stage_write = [&](int base) {
        *(bf16x8*)&smem[base + KT_OFF + t * 16]         = sk0;
        *(bf16x8*)&smem[base + KT_OFF + (t + 256) * 16] = sk1;
        *(bf16x8*)&smem[base + VT_OFF + t * 16]         = sv0;
        *(bf16x8*)&smem[base + VT_OFF + (t + 256) * 16] = sv1;
        if (t < 128) *(float2*)&smem[base + CK_OFF + t * 8] = sc2;
    };

    stage_load();
    stage_write(0);
    __syncthreads();
    int cur = 0;

    for (int kb = 0; kb < NQ; kb += 128) {
        const bool haveNext = (kb + 128 < NQ);
        const bool tail = (kb + 128 > NQ);
        if (haveNext) stage_load();               // issue early; hides under compute

        const int cb = cur * BUFSZ;
        float st[16];
        f32x4 cinit = {-mcur, -mcur, -mcur, -mcur};   // bake -m into MFMA C
#pragma unroll
        for (int kcl = 0; kcl < 4; ++kcl) {
            bf16x8 af = *(const bf16x8*)&smem[cb + KT_OFF + (((ksp * 4 + kcl) * 64 + lane) << 4)];
            f32x4 s = __builtin_amdgcn_mfma_f32_16x16x32_bf16(af, qf, cinit, 0, 0, 0);
            int lk = kwb + kcl * 16 + 4 * g;
            float4 cA = *(const float4*)&smem[cb + CK_OFF + lk * 8];
            float4 cB = *(const float4*)&smem[cb + CK_OFF + lk * 8 + 16];
            float cxv[4] = {cA.x, cA.z, cB.x, cB.z};
            float cyv[4] = {cA.y, cA.w, cB.y, cB.w};
#pragma unroll
            for (int r = 0; r < 4; ++r) {
                float dx = cqx - cxv[r], dy = cqy - cyv[r];
                float d2 = __builtin_fmaf(dx, dx, dy * dy);
                float dist = __builtin_amdgcn_sqrtf(d2);
                st[kcl * 4 + r] = __builtin_fmaf(dist, nbql, s[r]);
            }
            if (tail) {
#pragma unroll
                for (int r = 0; r < 4; ++r)
                    if (kb + lk + r >= NQ) st[kcl * 4 + r] = -1e30f;
            }
        }

        // ---- max via fmax3 trees + 2 shfl; defer-max (threshold on C-baked st) ----
        float a0 = fmaxf(fmaxf(st[0],  st[1]),  st[2]);
        float a1 = fmaxf(fmaxf(st[3],  st[4]),  st[5]);
        float a2 = fmaxf(fmaxf(st[6],  st[7]),  st[8]);
        float a3 = fmaxf(fmaxf(st[9],  st[10]), st[11]);
        float a4 = fmaxf(fmaxf(st[12], st[13]), st[14]);
        float vm = fmaxf(fmaxf(fmaxf(a0, a1), a2), fmaxf(fmaxf(a3, a4), st[15]));
        vm = fmaxf(vm, __shfl_xor(vm, 16));
        vm = fmaxf(vm, __shfl_xor(vm, 32));
        if (!__all(vm <= 8.0f)) {
            float dm = fmaxf(vm, 0.f);
            float al = __builtin_amdgcn_exp2f(-dm);
            mcur += dm;
            lsum *= al;
#pragma unroll
            for (int r = 0; r < 4; ++r) { o0[r] *= al; o1[r] *= al; }
#pragma unroll
            for (int x = 0; x < 16; ++x) st[x] -= dm;
        }
#pragma unroll
        for (int x = 0; x < 16; ++x) st[x] = __builtin_amdgcn_exp2f(st[x]);
        float s0 = (st[0] + st[1]) + (st[2] + st[3]);
        float s1 = (st[4] + st[5]) + (st[6] + st[7]);
        float s2 = (st[8] + st[9]) + (st[10] + st[11]);
        float s3 = (st[12] + st[13]) + (st[14] + st[15]);
        float rs = (s0 + s1) + (s2 + s3);
        rs += __shfl_xor(rs, 16);
        rs += __shfl_xor(rs, 32);
        lsum += rs;

        // ---- PV per 32-key chunk: P->LDS (b64 x2), read b128, 2 MFMA ----
#pragma unroll
        for (int kc2 = 0; kc2 < 2; ++kc2) {
#pragma unroll
            for (int kk = 0; kk < 2; ++kk) {
                int kcl = 2 * kc2 + kk;
                u32x2 pw = {pack2bf(st[kcl * 4 + 0], st[kcl * 4 + 1]),
                            pack2bf(st[kcl * 4 + 2], st[kcl * 4 + 3])};
                *(u32x2*)&smem[PL_OFF + (w << 10) + (((kk << 1) + (g >> 1)) << 8) + (i << 4) + ((g & 1) << 3)] = pw;
            }
            bf16x8 pbf = *(const bf16x8*)&smem[PL_OFF + (w << 10) + (g << 8) + (i << 4)];
            int vidx = (8 * ksp + 4 * kc2 + g) * 16 + i;
            bf16x8 vf0 = *(const bf16x8*)&smem[cb + VT_OFF + (vidx << 4)];
            bf16x8 vf1 = *(const bf16x8*)&smem[cb + VT_OFF + ((256 + vidx) << 4)];
            o0 = __builtin_amdgcn_mfma_f32_16x16x32_bf16(vf0, pbf, o0, 0, 0, 0);
            o1 = __builtin_amdgcn_mfma_f32_16x16x32_bf16(vf1, pbf, o1, 0, 0, 0);
        }

        if (haveNext) stage_write((cur ^ 1) * BUFSZ);   // other buffer: no read-drain needed
        __syncthreads();                                // publish next tile / pre-merge fence
        cur ^= 1;
    }

    // ---- merge the two key-splits per q-group (overlays smem) ----
    float* mrg = (float*)smem;                 // [4][64][10]
    float* my = mrg + (w * 64 + lane) * 10;
    my[0] = mcur; my[1] = lsum;
#pragma unroll
    for (int r = 0; r < 4; ++r) { my[2 + r] = o0[r]; my[6 + r] = o1[r]; }
    __syncthreads();
    const float* pr = mrg + ((w ^ 1) * 64 + lane) * 10;
    float m2 = pr[0], l2 = pr[1];
    float mN = fmaxf(mcur, m2);
    float a1 = __builtin_amdgcn_exp2f(mcur - mN);
    float a2 = __builtin_amdgcn_exp2f(m2 - mN);
    float inv = 1.f / (lsum * a1 + l2 * a2);
    int hh = w & 1;                            // this wave writes d-half hh
    f32x4 mine = hh ? o1 : o0;
    if (q < NQ) {
        short4 outv;
        float vals[4];
#pragma unroll
        for (int r = 0; r < 4; ++r) vals[r] = (mine[r] * a1 + pr[2 + hh * 4 + r] * a2) * inv;
        outv.x = f2bf(vals[0]); outv.y = f2bf(vals[1]);
        outv.z = f2bf(vals[2]); outv.w = f2bf(vals[3]);
        *(short4*)&attnb[(size_t)(bq + q) * DIM + h * HD + hh * 16 + 4 * g] = outv;
    }
}

extern "C" void kernel_launch(void* const* d_in, const int* in_sizes, int n_in,
                              void* d_out, int out_size, void* d_ws, size_t ws_size,
                              hipStream_t stream) {
    const float* bbox  = (const float*)d_in[0];
    const float* feat  = (const float*)d_in[1];
    const float* bw    = (const float*)d_in[2];
    const float* bb    = (const float*)d_in[3];
    const float* in_w  = (const float*)d_in[4];
    const float* in_b  = (const float*)d_in[5];
    const float* out_w = (const float*)d_in[6];
    const float* out_b = (const float*)d_in[7];
    float* out = (float*)d_out;

    char* ws = (char*)d_ws;
    size_t off = 0;
    auto alloc = [&](size_t bytes) { void* p = ws + off; off += (bytes + 255) & ~255ull; return p; };
    short* qkvb  = (short*)alloc((size_t)MROWS * E3 * 2);
    short* vtb   = (short*)alloc((size_t)BC * NH * VT2_PER_BH * 2);
    short* attnb = (short*)alloc((size_t)MROWS * DIM * 2);
    float* betab = (float*)alloc((size_t)BC * NH * NQ * 4);
    float* ctr   = (float*)alloc((size_t)BC * NQ * 2 * 4 + 1024);
    (void)ws_size; (void)in_sizes; (void)n_in; (void)out_size;

    beta_ctr_kernel<<<MROWS / 4, 256, 0, stream>>>(feat, bw, bb, bbox, betab, ctr);
    gemm_k256<true, true, false, true, true><<<dim3(E3 / 64, MROWS / 64), 256, 0, stream>>>(feat, in_w, in_b, qkvb, E3, vtb);
    attn_kernel<<<dim3((NQ + 31) / 32, BC * NH), 256, 0, stream>>>(qkvb, vtb, betab, ctr, attnb);
    gemm_k256<false, true, true, false, false><<<dim3(DIM / 64, MROWS / 64), 256, 0, stream>>>(attnb, out_w, out_b, out, DIM, nullptr);
}